// Round 9
// baseline (473.324 us; speedup 1.0000x reference)
//
#include <hip/hip_runtime.h>
#include <stdint.h>

#define BB 8
#define TT 256
#define DD 256
#define NSTEP 12
#define NNEG 100
#define K1_BLOCKS 768

typedef _Float16 h2 __attribute__((ext_vector_type(2)));
typedef _Float16 f16x8 __attribute__((ext_vector_type(8)));
typedef float f32x4 __attribute__((ext_vector_type(4)));

#if __has_builtin(__builtin_amdgcn_fdot2)
__device__ __forceinline__ float fdot2(h2 a, h2 b, float c) {
  return __builtin_amdgcn_fdot2(a, b, c, false);
}
#else
__device__ __forceinline__ float fdot2(h2 a, h2 b, float c) {
  return c + (float)a.x * (float)b.x + (float)a.y * (float)b.y;
}
#endif

// e5m2 byte -> f16 is an exact <<8. Expand dword [b3 b2 b1 b0] into two h2.
__device__ __forceinline__ h2 e5m2_lo(uint32_t w) {
#if __has_builtin(__builtin_amdgcn_perm)
  uint32_t r = __builtin_amdgcn_perm(0u, w, 0x010c000cu);
#else
  uint32_t r = ((w & 0xFFu) << 8) | ((w & 0xFF00u) << 16);
#endif
  union { uint32_t u; h2 h; } c; c.u = r; return c.h;
}
__device__ __forceinline__ h2 e5m2_hi(uint32_t w) {
#if __has_builtin(__builtin_amdgcn_perm)
  uint32_t r = __builtin_amdgcn_perm(0u, w, 0x030c020cu);
#else
  uint32_t r = ((w >> 8) & 0xFF00u) | ((w >> 16) & 0xFF000000u) | (((w >> 16) & 0xFFu) << 8);
#endif
  union { uint32_t u; h2 h; } c; c.u = r; return c.h;
}

// f32 -> e5m2 byte with RNE (values |x|<=1)
__device__ __forceinline__ uint32_t f32_to_e5m2(float f) {
  union { _Float16 h; uint16_t u; } c; c.h = (_Float16)f;
  uint16_t h = c.u;
  return (uint32_t)((uint16_t)(h + (uint16_t)0x7F + (uint16_t)((h >> 8) & 1u)) >> 8) & 0xFFu;
}

// ---------------- Threefry2x32 (JAX-compatible), host+device ----------------
__host__ __device__ __forceinline__ void tf2x32(uint32_t k0, uint32_t k1,
                                                uint32_t x0, uint32_t x1,
                                                uint32_t &y0, uint32_t &y1) {
  const uint32_t ks2 = k0 ^ k1 ^ 0x1BD11BDAu;
  x0 += k0; x1 += k1;
#define TF_R(r) { x0 += x1; x1 = (x1 << (r)) | (x1 >> (32 - (r))); x1 ^= x0; }
  TF_R(13) TF_R(15) TF_R(26) TF_R(6)
  x0 += k1; x1 += ks2 + 1u;
  TF_R(17) TF_R(29) TF_R(16) TF_R(24)
  x0 += ks2; x1 += k0 + 2u;
  TF_R(13) TF_R(15) TF_R(26) TF_R(6)
  x0 += k0; x1 += k1 + 3u;
  TF_R(17) TF_R(29) TF_R(16) TF_R(24)
  x0 += k1; x1 += ks2 + 4u;
  TF_R(13) TF_R(15) TF_R(26) TF_R(6)
  x0 += ks2; x1 += k0 + 5u;
#undef TF_R
  y0 = x0; y1 = x1;
}

// ---------------- host-computed per-step constants ----------------
struct IdxParams {
  uint32_t k1x[NSTEP], k1y[NSTEP], k2x[NSTEP], k2y[NSTEP];
  uint32_t mult[NSTEP];
  uint32_t Msp[NSTEP], Ssp[NSTEP], Asp[NSTEP];   // magic for span = 8*T2
  uint32_t Mt2[NSTEP], St2[NSTEP], At2[NSTEP];   // magic for T2
};

// Hacker's Delight 10-9 unsigned magic
static void magicu(uint32_t d, uint32_t* M, uint32_t* s, uint32_t* a) {
  uint32_t p, nc, delta, q1, r1, q2, r2;
  *a = 0;
  nc = 0xFFFFFFFFu - (0u - d) % d;
  p = 31;
  q1 = 0x80000000u / nc; r1 = 0x80000000u - q1 * nc;
  q2 = 0x7FFFFFFFu / d;  r2 = 0x7FFFFFFFu - q2 * d;
  do {
    p = p + 1;
    if (r1 >= nc - r1) { q1 = 2*q1 + 1; r1 = 2*r1 - nc; }
    else               { q1 = 2*q1;     r1 = 2*r1; }
    if (r2 + 1 >= d - r2) {
      if (q2 >= 0x7FFFFFFFu) *a = 1;
      q2 = 2*q2 + 1; r2 = 2*r2 + 1 - d;
    } else {
      if (q2 >= 0x80000000u) *a = 1;
      q2 = 2*q2; r2 = 2*r2 + 1;
    }
    delta = d - 1 - r2;
  } while (p < 64 && (q1 < delta || (q1 == delta && r1 == 0)));
  *M = q2 + 1; *s = p - 32;
}

__device__ __forceinline__ uint32_t mdiv(uint32_t n, uint32_t M, uint32_t s, uint32_t a) {
  uint32_t q = __umulhi(n, M);
  if (a) { q = ((n - q) >> 1) + q; return q >> (s - 1); }
  return q >> s;
}

// ------------- K1: prep phase + software grid barrier + f16 MFMA qgemm -------------
// grid 768 blocks x 256 thr; __launch_bounds__(256,3) guarantees 3 blocks/CU
// residency (768 = 3 x 256 CUs) so the spin barrier cannot deadlock.
__global__ __launch_bounds__(256, 3) void k1_prep_qgemm(const float* __restrict__ tgt,
                                                        const float* __restrict__ ctx,
                                                        const float* __restrict__ W,
                                                        const float* __restrict__ bias,
                                                        uint8_t* __restrict__ tn8,
                                                        _Float16* __restrict__ ctxh,
                                                        _Float16* __restrict__ Wh,
                                                        _Float16* __restrict__ qnh,
                                                        uint32_t* __restrict__ barrier_cnt) {
  const int bx   = blockIdx.x;
  const int tid  = threadIdx.x;
  const int lane = tid & 63;

  // ---- phase A: 7168 row tasks over 3072 waves ----
  const int gw = bx * 4 + (tid >> 6);
  for (int task = gw; task < 7168; task += 3072) {
    if (task < 2048) {                              // tgt row: l2norm -> e5m2
      float4 v = ((const float4*)(tgt + (size_t)task * DD))[lane];
      float ss = v.x*v.x + v.y*v.y + v.z*v.z + v.w*v.w;
#pragma unroll
      for (int off = 1; off < 64; off <<= 1) ss += __shfl_xor(ss, off, 64);
      const float sc = 1.0f / fmaxf(sqrtf(ss), 1e-12f);
      const uint32_t p = f32_to_e5m2(v.x * sc) | (f32_to_e5m2(v.y * sc) << 8)
                       | (f32_to_e5m2(v.z * sc) << 16) | (f32_to_e5m2(v.w * sc) << 24);
      ((uint32_t*)(tn8 + (size_t)task * DD))[lane] = p;
    } else {
      union { _Float16 h[4]; uint2 u; } o;
      if (task < 4096) {                            // ctx row -> f16
        const int row = task - 2048;
        float4 v = ((const float4*)(ctx + (size_t)row * DD))[lane];
        o.h[0] = (_Float16)v.x; o.h[1] = (_Float16)v.y;
        o.h[2] = (_Float16)v.z; o.h[3] = (_Float16)v.w;
        ((uint2*)(ctxh + (size_t)row * DD))[lane] = o.u;
      } else {                                      // W row (3072 rows) -> f16
        const int row = task - 4096;
        float4 v = ((const float4*)(W + (size_t)row * DD))[lane];
        o.h[0] = (_Float16)v.x; o.h[1] = (_Float16)v.y;
        o.h[2] = (_Float16)v.z; o.h[3] = (_Float16)v.w;
        ((uint2*)(Wh + (size_t)row * DD))[lane] = o.u;
      }
    }
  }

  // ---- software grid barrier (all 768 blocks co-resident) ----
  __syncthreads();
  if (tid == 0) {
    __threadfence();
    atomicAdd(barrier_cnt, 1u);
    while (atomicAdd(barrier_cnt, 0u) < (uint32_t)K1_BLOCKS)
      __builtin_amdgcn_s_sleep(2);
    __threadfence();
  }
  __syncthreads();

  // ---- phase B: qgemm (R5-proven f16 MFMA body) ----
  const int mt = bx & 63;               // 0..63
  const int s  = bx >> 6;               // 0..11
  const int w  = tid >> 6;
  const int sl = lane & 15;
  const int q  = lane >> 4;
  const int m0 = mt * 32;

  const _Float16* Arow0 = ctxh + ((size_t)(m0 + sl)) * DD + q * 8;
  const _Float16* Arow1 = Arow0 + (size_t)16 * DD;
  const _Float16* Bbase = Wh + (size_t)s * DD * DD + ((size_t)(w * 64 + sl)) * DD + q * 8;

  f32x4 acc[2][4];
#pragma unroll
  for (int mi = 0; mi < 2; ++mi)
#pragma unroll
    for (int nt = 0; nt < 4; ++nt) acc[mi][nt] = f32x4{0, 0, 0, 0};

#pragma unroll
  for (int k0 = 0; k0 < 8; ++k0) {
    const f16x8 a0 = *(const f16x8*)(Arow0 + k0 * 32);
    const f16x8 a1 = *(const f16x8*)(Arow1 + k0 * 32);
#pragma unroll
    for (int nt = 0; nt < 4; ++nt) {
      const f16x8 b = *(const f16x8*)(Bbase + (size_t)nt * 16 * DD + k0 * 32);
      acc[0][nt] = __builtin_amdgcn_mfma_f32_16x16x32_f16(a0, b, acc[0][nt], 0, 0, 0);
      acc[1][nt] = __builtin_amdgcn_mfma_f32_16x16x32_f16(a1, b, acc[1][nt], 0, 0, 0);
    }
  }
  const float* bp = bias + (size_t)s * DD + w * 64 + sl;
  __shared__ float part[4][32];
#pragma unroll
  for (int mi = 0; mi < 2; ++mi) {
#pragma unroll
    for (int nt = 0; nt < 4; ++nt) {
      const float bv = bp[nt * 16];
#pragma unroll
      for (int r = 0; r < 4; ++r) acc[mi][nt][r] += bv;
    }
    float ss[4];
#pragma unroll
    for (int r = 0; r < 4; ++r) {
      float v = 0.f;
#pragma unroll
      for (int nt = 0; nt < 4; ++nt) v += acc[mi][nt][r] * acc[mi][nt][r];
      ss[r] = v;
    }
#pragma unroll
    for (int off = 1; off < 16; off <<= 1) {
#pragma unroll
      for (int r = 0; r < 4; ++r) ss[r] += __shfl_xor(ss[r], off, 64);
    }
    if (sl == 0) {
#pragma unroll
      for (int r = 0; r < 4; ++r) part[w][mi * 16 + q * 4 + r] = ss[r];
    }
  }
  __syncthreads();
#pragma unroll
  for (int mi = 0; mi < 2; ++mi) {
#pragma unroll
    for (int r = 0; r < 4; ++r) {
      const int row = q * 4 + r;
      const float tot = part[0][mi * 16 + row] + part[1][mi * 16 + row]
                      + part[2][mi * 16 + row] + part[3][mi * 16 + row];
      const float sc = 1.0f / fmaxf(sqrtf(tot), 1e-12f);
      _Float16* outp = qnh + (((size_t)s * (BB * TT)) + m0 + mi * 16 + row) * DD + w * 64 + sl;
#pragma unroll
      for (int nt = 0; nt < 4; ++nt) outp[nt * 16] = (_Float16)(acc[mi][nt][r] * sc);
    }
  }
}

// ------------- K2: score (threefry idx + e5m2 gather + log-softmax) + atomicAdd -------------
__global__ __launch_bounds__(128) void score_kernel(const IdxParams P,
                                                    const _Float16* __restrict__ qnh,
                                                    const uint8_t* __restrict__ tn8,
                                                    float* __restrict__ out) {
  const int t    = blockIdx.x;            // 0..254
  const int b    = blockIdx.y;
  const int si   = blockIdx.z;
  const int step = si + 1;
  const int T2   = TT - step;
  const int tid  = threadIdx.x;
  if (t >= T2) return;

  __shared__ int   rowIdx[NNEG + 1];
  __shared__ float logit[NNEG + 1];

  if (tid < NNEG) {
    const uint32_t span = (uint32_t)(BB * T2);
    const uint32_t j = (uint32_t)((b * T2 + t) * NNEG + tid);
    uint32_t h0, h1, l0, l1;
    tf2x32(P.k1x[si], P.k1y[si], 0u, j, h0, h1);
    tf2x32(P.k2x[si], P.k2y[si], 0u, j, l0, l1);
    const uint32_t Msp = P.Msp[si], Ssp = P.Ssp[si], Asp = P.Asp[si];
    const uint32_t hm = h0 - mdiv(h0, Msp, Ssp, Asp) * span;
    const uint32_t lm = l0 - mdiv(l0, Msp, Ssp, Asp) * span;
    const uint32_t off = hm * P.mult[si] + lm;
    const uint32_t om = off - mdiv(off, Msp, Ssp, Asp) * span;
    const uint32_t bb = mdiv(om, P.Mt2[si], P.St2[si], P.At2[si]);
    const uint32_t tt = om - bb * (uint32_t)T2;
    rowIdx[tid + 1] = (int)(bb * TT + tt + (uint32_t)step);
  } else if (tid == NNEG) {
    rowIdx[0] = b * TT + t + step;        // positive row
  }

  const int g  = tid >> 2;                // dot-group 0..31
  const int gl = tid & 3;                 // lane-in-group
  const _Float16* qrow = qnh + (((size_t)si * (BB * TT)) + b * TT + t) * DD;
  uint4 qv[8];
#pragma unroll
  for (int c = 0; c < 4; ++c) {
    qv[c * 2]     = *(const uint4*)(qrow + c * 64 + gl * 16);
    qv[c * 2 + 1] = *(const uint4*)(qrow + c * 64 + gl * 16 + 8);
  }
  __syncthreads();

#pragma unroll
  for (int r = 0; r < 4; ++r) {
    const int k = r * 32 + g;
    if (k <= NNEG) {
      const uint8_t* prow = tn8 + (size_t)rowIdx[k] * DD;
      float d0 = 0.f, d1 = 0.f, d2 = 0.f, d3 = 0.f;
#pragma unroll
      for (int c = 0; c < 4; ++c) {
        const uint4 pv = *(const uint4*)(prow + c * 64 + gl * 16);
        union { uint4 u; h2 h[4]; } qa, qb;
        qa.u = qv[c * 2]; qb.u = qv[c * 2 + 1];
        d0 = fdot2(qa.h[0], e5m2_lo(pv.x), d0);
        d1 = fdot2(qa.h[1], e5m2_hi(pv.x), d1);
        d2 = fdot2(qa.h[2], e5m2_lo(pv.y), d2);
        d3 = fdot2(qa.h[3], e5m2_hi(pv.y), d3);
        d0 = fdot2(qb.h[0], e5m2_lo(pv.z), d0);
        d1 = fdot2(qb.h[1], e5m2_hi(pv.z), d1);
        d2 = fdot2(qb.h[2], e5m2_lo(pv.w), d2);
        d3 = fdot2(qb.h[3], e5m2_hi(pv.w), d3);
      }
      float d = (d0 + d1) + (d2 + d3);
      d += __shfl_xor(d, 1, 64);
      d += __shfl_xor(d, 2, 64);
      if (gl == 0) logit[k] = d * 10.0f;  // 1/TEMP
    }
  }
  __syncthreads();

  if (tid < 64) {
    const float a = logit[tid];
    const float c = (tid + 64 <= NNEG) ? logit[tid + 64] : -1e30f;
    float m = fmaxf(a, c);
#pragma unroll
    for (int off = 1; off < 64; off <<= 1) m = fmaxf(m, __shfl_xor(m, off, 64));
    float e = __expf(a - m) + ((tid + 64 <= NNEG) ? __expf(c - m) : 0.f);
#pragma unroll
    for (int off = 1; off < 64; off <<= 1) e += __shfl_xor(e, off, 64);
    if (tid == 0) {
      const float lse = m + logf(e);
      atomicAdd(out, (lse - logit[0]) / (12.0f * (float)(BB * T2)));
    }
  }
}

extern "C" void kernel_launch(void* const* d_in, const int* in_sizes, int n_in,
                              void* d_out, int out_size, void* d_ws, size_t ws_size,
                              hipStream_t stream) {
  const float* ctx  = (const float*)d_in[0];
  const float* tgt  = (const float*)d_in[1];
  const float* W    = (const float*)d_in[2];
  const float* bias = (const float*)d_in[3];
  float* out = (float*)d_out;

  uint8_t* tn8   = (uint8_t*)d_ws;                             // 512 KB
  _Float16* ctxh = (_Float16*)(tn8 + (size_t)BB * TT * DD);    // 1 MB
  _Float16* Wh   = ctxh + (size_t)BB * TT * DD;                // 1.5 MB
  _Float16* qnh  = Wh + (size_t)NSTEP * DD * DD;               // 12.6 MB
  uint32_t* cnt  = (uint32_t*)(qnh + (size_t)NSTEP * BB * TT * DD);

  // host-side per-step constants (deterministic; same every call)
  IdxParams P;
  for (int s = 0; s < NSTEP; ++s) {
    uint32_t a, b;
    tf2x32(0u, 1234u, 0u, (uint32_t)(s + 1), a, b);            // fold_in(key(1234), step)
    uint32_t h1a, h1b, h2a, h2b;
    tf2x32(a, b, 0u, 2u, h1a, h1b);                            // split -> k1
    tf2x32(a, b, 1u, 3u, h2a, h2b);                            // split -> k2
    P.k1x[s] = h1a; P.k1y[s] = h1b; P.k2x[s] = h2a; P.k2y[s] = h2b;
    const uint32_t T2 = (uint32_t)(TT - (s + 1));
    const uint32_t span = 8u * T2;
    uint32_t m = 65536u % span;
    P.mult[s] = (uint32_t)(((uint64_t)m * m) % span);
    magicu(span, &P.Msp[s], &P.Ssp[s], &P.Asp[s]);
    magicu(T2,   &P.Mt2[s], &P.St2[s], &P.At2[s]);
  }

  hipMemsetAsync(out, 0, sizeof(float), stream);
  hipMemsetAsync(cnt, 0, sizeof(uint32_t), stream);
  hipLaunchKernelGGL(k1_prep_qgemm, dim3(K1_BLOCKS), dim3(256), 0, stream,
                     tgt, ctx, W, bias, tn8, ctxh, Wh, qnh, cnt);
  hipLaunchKernelGGL(score_kernel, dim3(255, BB, NSTEP), dim3(128), 0, stream,
                     P, qnh, tn8, out);
}